// Round 2
// baseline (343.579 us; speedup 1.0000x reference)
//
#include <hip/hip_runtime.h>
#include <stdint.h>

// Problem constants (B=4, S=2048 -> M = 8192 rows)
#define M_TOT 8192
#define N_TOT 4096
#define K_TOT 4096

typedef int v4i __attribute__((ext_vector_type(4)));

// ---------------------------------------------------------------------------
// Kernel 0: pack weight int32 -> int8 (harness passes integer inputs as int32)
// ---------------------------------------------------------------------------
__global__ void pack_w(const int4* __restrict__ w32, int* __restrict__ w8, int n4) {
  int stride = gridDim.x * blockDim.x;
  for (int i = blockIdx.x * blockDim.x + threadIdx.x; i < n4; i += stride) {
    int4 v = w32[i];
    w8[i] = (v.x & 0xff) | ((v.y & 0xff) << 8) | ((v.z & 0xff) << 16) | (v.w << 24);
  }
}

// ---------------------------------------------------------------------------
// Kernel 1: global max(|x / smooth|) -> ws[0] as uint bits (values >= 0)
// ---------------------------------------------------------------------------
__global__ void reduce_maxabs(const float4* __restrict__ x,
                              const float4* __restrict__ smooth4,
                              unsigned int* __restrict__ maxbits, int n4) {
  float m = 0.0f;
  int stride = gridDim.x * blockDim.x;
  for (int i = blockIdx.x * blockDim.x + threadIdx.x; i < n4; i += stride) {
    float4 v = x[i];
    float4 s = smooth4[i & (K_TOT / 4 - 1)];
    m = fmaxf(m, fabsf(v.x / s.x));
    m = fmaxf(m, fabsf(v.y / s.y));
    m = fmaxf(m, fabsf(v.z / s.z));
    m = fmaxf(m, fabsf(v.w / s.w));
  }
#pragma unroll
  for (int off = 32; off; off >>= 1) m = fmaxf(m, __shfl_xor(m, off));
  if ((threadIdx.x & 63) == 0) atomicMax(maxbits, __float_as_uint(m));
}

// ---------------------------------------------------------------------------
// Kernel 2: quantize x -> int8 (packed char4), per-tensor scale
// q = clip(rint((x/s) / (max/127 + 1e-5)), -128, 127)
// ---------------------------------------------------------------------------
__global__ void quantize_x(const float4* __restrict__ x,
                           const float4* __restrict__ smooth4,
                           const unsigned int* __restrict__ maxbits,
                           int* __restrict__ xq, int n4) {
  float act_scale = __uint_as_float(*maxbits) / 127.0f;
  float d = act_scale + 1e-5f;
  int stride = gridDim.x * blockDim.x;
  for (int i = blockIdx.x * blockDim.x + threadIdx.x; i < n4; i += stride) {
    float4 v = x[i];
    float4 s = smooth4[i & (K_TOT / 4 - 1)];
    int q0 = (int)fminf(fmaxf(rintf((v.x / s.x) / d), -128.0f), 127.0f);
    int q1 = (int)fminf(fmaxf(rintf((v.y / s.y) / d), -128.0f), 127.0f);
    int q2 = (int)fminf(fmaxf(rintf((v.z / s.z) / d), -128.0f), 127.0f);
    int q3 = (int)fminf(fmaxf(rintf((v.w / s.w) / d), -128.0f), 127.0f);
    xq[i] = (q0 & 0xff) | ((q1 & 0xff) << 8) | ((q2 & 0xff) << 16) | (q3 << 24);
  }
}

// ---------------------------------------------------------------------------
// Kernel 3: int8 GEMM, C[m][n] = sum_k Aq[m][k] * Wt[n][k]  (both row-major [*, K])
// 128x128 tile, BK=64, 4 waves (2x2), each wave 64x64 out = 4x4 frags of 16x16.
// mfma_i32_16x16x64_i8 : one MFMA consumes full BK=64.
// Epilogue: out = acc * (max/127) * wscale[n] + bias[n]
// ---------------------------------------------------------------------------
__global__ __launch_bounds__(256) void gemm_i8(
    const int8_t* __restrict__ Aq,   // [M][K]
    const int8_t* __restrict__ Wt,   // [N][K]
    const unsigned int* __restrict__ maxbits,
    const float* __restrict__ wscale,  // [N]
    const float* __restrict__ bias,    // [N]
    float* __restrict__ out) {         // [M][N]
  __shared__ int8_t As[128 * 64];
  __shared__ int8_t Bs[128 * 64];

  const int lane = threadIdx.x & 63;
  const int wave = threadIdx.x >> 6;
  const int m0 = blockIdx.y * 128;
  const int n0 = blockIdx.x * 128;
  const int wm = (wave >> 1) * 64;  // wave row offset in tile
  const int wn = (wave & 1) * 64;   // wave col offset in tile
  const int l16 = lane & 15;
  const int lhi = lane >> 4;

  // staging: tile is 8192 B = 8 wave-chunks of 1024 B; each wave does 2 chunks
  const int sbase0 = wave * 1024;
  const int sbase1 = (4 + wave) * 1024;
  const int idx0 = sbase0 + lane * 16;
  const int idx1 = sbase1 + lane * 16;
  const int row0 = idx0 >> 6, col0 = idx0 & 63;
  const int row1 = idx1 >> 6, col1 = idx1 & 63;
  const int8_t* gA0 = Aq + (size_t)(m0 + row0) * K_TOT + col0;
  const int8_t* gA1 = Aq + (size_t)(m0 + row1) * K_TOT + col1;
  const int8_t* gB0 = Wt + (size_t)(n0 + row0) * K_TOT + col0;
  const int8_t* gB1 = Wt + (size_t)(n0 + row1) * K_TOT + col1;

  v4i acc[4][4] = {};

  // fragment LDS addresses (constant per thread)
  const int8_t* pa = As + (wm + l16) * 64 + lhi * 16;
  const int8_t* pb = Bs + (wn + l16) * 64 + lhi * 16;

  for (int k0 = 0; k0 < K_TOT; k0 += 64) {
    __builtin_amdgcn_global_load_lds(
        (const __attribute__((address_space(1))) void*)(gA0 + k0),
        (__attribute__((address_space(3))) void*)(As + sbase0), 16, 0, 0);
    __builtin_amdgcn_global_load_lds(
        (const __attribute__((address_space(1))) void*)(gA1 + k0),
        (__attribute__((address_space(3))) void*)(As + sbase1), 16, 0, 0);
    __builtin_amdgcn_global_load_lds(
        (const __attribute__((address_space(1))) void*)(gB0 + k0),
        (__attribute__((address_space(3))) void*)(Bs + sbase0), 16, 0, 0);
    __builtin_amdgcn_global_load_lds(
        (const __attribute__((address_space(1))) void*)(gB1 + k0),
        (__attribute__((address_space(3))) void*)(Bs + sbase1), 16, 0, 0);
    __syncthreads();

    v4i a[4], b[4];
#pragma unroll
    for (int i = 0; i < 4; ++i) a[i] = *(const v4i*)(pa + i * 16 * 64);
#pragma unroll
    for (int j = 0; j < 4; ++j) b[j] = *(const v4i*)(pb + j * 16 * 64);
#pragma unroll
    for (int i = 0; i < 4; ++i)
#pragma unroll
      for (int j = 0; j < 4; ++j)
        acc[i][j] = __builtin_amdgcn_mfma_i32_16x16x64_i8(a[i], b[j], acc[i][j], 0, 0, 0);
    __syncthreads();
  }

  const float ascale = __uint_as_float(*maxbits) / 127.0f;
#pragma unroll
  for (int i = 0; i < 4; ++i) {
    const int orow = m0 + wm + i * 16 + lhi * 4;
#pragma unroll
    for (int j = 0; j < 4; ++j) {
      const int ocol = n0 + wn + j * 16 + l16;
      const float wsc = wscale[ocol] * ascale;
      const float bb = bias[ocol];
#pragma unroll
      for (int r = 0; r < 4; ++r) {
        out[(size_t)(orow + r) * N_TOT + ocol] = (float)acc[i][j][r] * wsc + bb;
      }
    }
  }
}

// ---------------------------------------------------------------------------
extern "C" void kernel_launch(void* const* d_in, const int* in_sizes, int n_in,
                              void* d_out, int out_size, void* d_ws, size_t ws_size,
                              hipStream_t stream) {
  const float* x = (const float*)d_in[0];
  const int* w32 = (const int*)d_in[1];        // int8 in reference, int32 on device
  const float* wscale = (const float*)d_in[2];
  const float* smooth = (const float*)d_in[3];
  const float* bias = (const float*)d_in[4];
  float* out = (float*)d_out;

  unsigned int* maxbits = (unsigned int*)d_ws;
  int8_t* xq = (int8_t*)d_ws + 256;                    // M*K int8 = 33.5 MB
  int8_t* wq8 = xq + (size_t)M_TOT * K_TOT;            // N*K int8 = 16.8 MB

  hipMemsetAsync(d_ws, 0, 4, stream);  // zero the max accumulator each call

  const int nw4 = N_TOT * K_TOT / 4;
  pack_w<<<2048, 256, 0, stream>>>((const int4*)w32, (int*)wq8, nw4);

  const int n4 = M_TOT * K_TOT / 4;
  reduce_maxabs<<<2048, 256, 0, stream>>>((const float4*)x, (const float4*)smooth,
                                          maxbits, n4);
  quantize_x<<<2048, 256, 0, stream>>>((const float4*)x, (const float4*)smooth,
                                       maxbits, (int*)xq, n4);

  dim3 grid(N_TOT / 128, M_TOT / 128);
  gemm_i8<<<grid, 256, 0, stream>>>(xq, wq8, maxbits, wscale, bias, out);
}

// Round 3
// 232.546 us; speedup vs baseline: 1.4775x; 1.4775x over previous
//
#include <hip/hip_runtime.h>
#include <stdint.h>

// Problem constants (B=4, S=2048 -> M = 8192 rows)
#define M_TOT 8192
#define N_TOT 4096
#define K_TOT 4096

typedef int v4i __attribute__((ext_vector_type(4)));

// GEMM tile config: 256x256 tile, BK=128 bytes of K, 8 waves (2M x 4N), 512 thr
#define BM 256
#define BN 256
#define BK 128
#define NT (K_TOT / BK)                    // 32 K-tiles
#define TILE_A_BYTES (BM * BK)             // 32 KB
#define TILE_B_BYTES (BN * BK)             // 32 KB
#define BUF_BYTES (TILE_A_BYTES + TILE_B_BYTES)  // 64 KB, x2 buffers = 128 KB LDS

// ---------------------------------------------------------------------------
// Kernel 0: rcp table  r[k] = 1/smooth[k]
// ---------------------------------------------------------------------------
__global__ void prep_rcp(const float* __restrict__ s, float* __restrict__ r) {
  int i = blockIdx.x * blockDim.x + threadIdx.x;
  if (i < K_TOT) r[i] = 1.0f / s[i];
}

// ---------------------------------------------------------------------------
// Kernel 1: pack weight int32 -> int8 (harness passes integer inputs as int32)
// ---------------------------------------------------------------------------
__global__ void pack_w(const int4* __restrict__ w32, int* __restrict__ w8, int n4) {
  int stride = gridDim.x * blockDim.x;
  for (int i = blockIdx.x * blockDim.x + threadIdx.x; i < n4; i += stride) {
    int4 v = w32[i];
    w8[i] = (v.x & 0xff) | ((v.y & 0xff) << 8) | ((v.z & 0xff) << 16) | (v.w << 24);
  }
}

// ---------------------------------------------------------------------------
// Kernel 2: global max(|x * rcp_s|) -> ws[0] as uint bits; 1 atomic per block
// ---------------------------------------------------------------------------
__global__ void reduce_maxabs(const float4* __restrict__ x,
                              const float4* __restrict__ rcp4,
                              unsigned int* __restrict__ maxbits, int n4) {
  float m = 0.0f;
  int stride = gridDim.x * blockDim.x;
  for (int i = blockIdx.x * blockDim.x + threadIdx.x; i < n4; i += stride) {
    float4 v = x[i];
    float4 r = rcp4[i & (K_TOT / 4 - 1)];
    m = fmaxf(m, fabsf(v.x * r.x));
    m = fmaxf(m, fabsf(v.y * r.y));
    m = fmaxf(m, fabsf(v.z * r.z));
    m = fmaxf(m, fabsf(v.w * r.w));
  }
#pragma unroll
  for (int off = 32; off; off >>= 1) m = fmaxf(m, __shfl_xor(m, off));
  __shared__ float sm[4];
  if ((threadIdx.x & 63) == 0) sm[threadIdx.x >> 6] = m;
  __syncthreads();
  if (threadIdx.x == 0) {
    float mm = fmaxf(fmaxf(sm[0], sm[1]), fmaxf(sm[2], sm[3]));
    atomicMax(maxbits, __float_as_uint(mm));
  }
}

// ---------------------------------------------------------------------------
// Kernel 3: quantize x -> int8 packed; q = clip(rint(x * rcp_s * inv_d))
// ---------------------------------------------------------------------------
__global__ void quantize_x(const float4* __restrict__ x,
                           const float4* __restrict__ rcp4,
                           const unsigned int* __restrict__ maxbits,
                           int* __restrict__ xq, int n4) {
  const float d = __uint_as_float(*maxbits) / 127.0f + 1e-5f;
  const float inv = 1.0f / d;
  int stride = gridDim.x * blockDim.x;
  for (int i = blockIdx.x * blockDim.x + threadIdx.x; i < n4; i += stride) {
    float4 v = x[i];
    float4 r = rcp4[i & (K_TOT / 4 - 1)];
    int q0 = (int)fminf(fmaxf(rintf(v.x * r.x * inv), -128.0f), 127.0f);
    int q1 = (int)fminf(fmaxf(rintf(v.y * r.y * inv), -128.0f), 127.0f);
    int q2 = (int)fminf(fmaxf(rintf(v.z * r.z * inv), -128.0f), 127.0f);
    int q3 = (int)fminf(fmaxf(rintf(v.w * r.w * inv), -128.0f), 127.0f);
    xq[i] = (q0 & 0xff) | ((q1 & 0xff) << 8) | ((q2 & 0xff) << 16) | (q3 << 24);
  }
}

// ---------------------------------------------------------------------------
// Kernel 4: int8 GEMM, 256x256 tile, BK=128, counted-vmcnt double buffer.
//
// Race-freedom argument (per K-tile iteration t, reading buf[t&1]):
//   1. all 24 ds_read_b128 of buf[t&1] -> lgkmcnt(0) -> s_barrier
//      => every wave's reads COMPLETED before anyone proceeds.
//   2. issue 8 global_load_lds for tile t+2 into buf[t&1]  (safe: reads done)
//   3. 64 MFMA under setprio(1)
//   4. s_waitcnt vmcnt(8): outstanding <= 16 (t+1's 8 + t+2's 8); waiting to 8
//      drains the OLDEST 8 = tile t+1's loads -> t+1 fully in LDS.
//   5. s_barrier => ALL waves' t+1 loads landed; next iter reads buf[(t+1)&1].
// vmcnt never drains to 0 in the loop (T4); loads span two barriers.
//
// LDS swizzle (T2): physical col = logical col ^ ((row&7)<<4), applied on the
// pre-swizzled GLOBAL source (global_load_lds writes linearly) and on ds_read.
// Fragment reads then spread 16 lanes over 8 16B-slots => 2-way = free.
// ---------------------------------------------------------------------------
__global__ __launch_bounds__(512, 2) void gemm_i8(
    const int8_t* __restrict__ Aq,   // [M][K]
    const int8_t* __restrict__ Wt,   // [N][K]
    const unsigned int* __restrict__ maxbits,
    const float* __restrict__ wscale,  // [N]
    const float* __restrict__ bias,    // [N]
    float* __restrict__ out) {         // [M][N]
  __shared__ int8_t lds[2 * BUF_BYTES];

  const int tid = threadIdx.x;
  const int lane = tid & 63;
  const int wid = tid >> 6;      // 0..7
  const int l16 = lane & 15;
  const int lhi = lane >> 4;     // 0..3
  const int m0 = blockIdx.y * BM;
  const int n0 = blockIdx.x * BN;
  const int wave_m = wid >> 2;   // 0..1  -> 128 rows
  const int wave_n = wid & 3;    // 0..3  -> 64 cols

  // ---- staging: per wave 4 A-chunks + 4 B-chunks, 1 KB each (8 rows x 128B)
  const int roff = lane >> 3;                    // row within chunk 0..7
  const int csel = ((lane & 7) ^ roff) << 4;     // pre-swizzled 16B col block
  const int8_t* Abase = Aq + (size_t)m0 * K_TOT; // uniform
  const int8_t* Bbase = Wt + (size_t)n0 * K_TOT; // uniform
  int goff[4];
#pragma unroll
  for (int c = 0; c < 4; ++c) {
    int grow = (wid * 4 + c) * 8 + roff;         // 0..255
    goff[c] = grow * K_TOT + csel;
  }

  auto stage = [&](int dstbuf, int koff) {
#pragma unroll
    for (int c = 0; c < 4; ++c) {
      __builtin_amdgcn_global_load_lds(
          (const __attribute__((address_space(1))) void*)(Abase + goff[c] + koff),
          (__attribute__((address_space(3))) void*)(lds + dstbuf * BUF_BYTES + (wid * 4 + c) * 1024),
          16, 0, 0);
      __builtin_amdgcn_global_load_lds(
          (const __attribute__((address_space(1))) void*)(Bbase + goff[c] + koff),
          (__attribute__((address_space(3))) void*)(lds + dstbuf * BUF_BYTES + TILE_A_BYTES + (wid * 4 + c) * 1024),
          16, 0, 0);
    }
  };

  // ---- ds_read fragment addressing (swizzled) ----
  const int sw = (l16 & 7) << 4;
  const int colA0 = (0 * 64 + lhi * 16) ^ sw;   // kstep 0
  const int colA1 = (1 * 64 + lhi * 16) ^ sw;   // kstep 1
  const int aRow = (wave_m * 128 + l16) * BK;
  const int bRow = (wave_n * 64 + l16) * BK;

  // ---- prologue: stage tiles 0,1; wait tile 0 landed ----
  stage(0, 0);
  stage(1, BK);
  asm volatile("s_waitcnt vmcnt(8)" ::: "memory");
  __builtin_amdgcn_s_barrier();
  __builtin_amdgcn_sched_barrier(0);

  v4i acc[8][4] = {};

#pragma unroll 2
  for (int t = 0; t < NT; ++t) {
    const int buf = t & 1;
    const int8_t* Ab = lds + buf * BUF_BYTES;
    const int8_t* Bb = lds + buf * BUF_BYTES + TILE_A_BYTES;

    v4i a0[8], a1[8], b0[4], b1[4];
#pragma unroll
    for (int i = 0; i < 8; ++i) {
      a0[i] = *(const v4i*)(Ab + aRow + i * 2048 + colA0);
      a1[i] = *(const v4i*)(Ab + aRow + i * 2048 + colA1);
    }
#pragma unroll
    for (int j = 0; j < 4; ++j) {
      b0[j] = *(const v4i*)(Bb + bRow + j * 2048 + colA0);
      b1[j] = *(const v4i*)(Bb + bRow + j * 2048 + colA1);
    }
    asm volatile("s_waitcnt lgkmcnt(0)" ::: "memory");
    __builtin_amdgcn_sched_barrier(0);
    __builtin_amdgcn_s_barrier();
    __builtin_amdgcn_sched_barrier(0);

    // stage tile t+2 into the buffer we just finished reading
    const int ts = (t + 2 < NT) ? (t + 2) : (NT - 1);
    stage(buf, ts * BK);
    __builtin_amdgcn_sched_barrier(0);

    __builtin_amdgcn_s_setprio(1);
#pragma unroll
    for (int i = 0; i < 8; ++i)
#pragma unroll
      for (int j = 0; j < 4; ++j) {
        acc[i][j] = __builtin_amdgcn_mfma_i32_16x16x64_i8(a0[i], b0[j], acc[i][j], 0, 0, 0);
        acc[i][j] = __builtin_amdgcn_mfma_i32_16x16x64_i8(a1[i], b1[j], acc[i][j], 0, 0, 0);
      }
    __builtin_amdgcn_s_setprio(0);
    __builtin_amdgcn_sched_barrier(0);

    asm volatile("s_waitcnt vmcnt(8)" ::: "memory");
    __builtin_amdgcn_sched_barrier(0);
    __builtin_amdgcn_s_barrier();
    __builtin_amdgcn_sched_barrier(0);
  }

  // ---- epilogue: dequant + bias, C/D layout col=l16, row=lhi*4+reg ----
  const float ascale = __uint_as_float(*maxbits) / 127.0f;
#pragma unroll
  for (int i = 0; i < 8; ++i) {
    const int orow = m0 + wave_m * 128 + i * 16 + lhi * 4;
#pragma unroll
    for (int j = 0; j < 4; ++j) {
      const int ocol = n0 + wave_n * 64 + j * 16 + l16;
      const float wsc = wscale[ocol] * ascale;
      const float bb = bias[ocol];
#pragma unroll
      for (int r = 0; r < 4; ++r) {
        out[(size_t)(orow + r) * N_TOT + ocol] = (float)acc[i][j][r] * wsc + bb;
      }
    }
  }
}

// ---------------------------------------------------------------------------
extern "C" void kernel_launch(void* const* d_in, const int* in_sizes, int n_in,
                              void* d_out, int out_size, void* d_ws, size_t ws_size,
                              hipStream_t stream) {
  const float* x = (const float*)d_in[0];
  const int* w32 = (const int*)d_in[1];        // int8 in reference, int32 on device
  const float* wscale = (const float*)d_in[2];
  const float* smooth = (const float*)d_in[3];
  const float* bias = (const float*)d_in[4];
  float* out = (float*)d_out;

  unsigned int* maxbits = (unsigned int*)d_ws;
  float* rcp = (float*)((char*)d_ws + 1024);                 // 16 KB
  int8_t* xq = (int8_t*)d_ws + (1 << 20);                    // 32 MB
  int8_t* wq8 = xq + (size_t)M_TOT * K_TOT;                  // 16 MB

  hipMemsetAsync(d_ws, 0, 4, stream);  // zero the max accumulator each call

  prep_rcp<<<K_TOT / 256, 256, 0, stream>>>(smooth, rcp);

  const int nw4 = N_TOT * K_TOT / 4;
  pack_w<<<2048, 256, 0, stream>>>((const int4*)w32, (int*)wq8, nw4);

  const int n4 = M_TOT * K_TOT / 4;
  reduce_maxabs<<<2048, 256, 0, stream>>>((const float4*)x, (const float4*)rcp,
                                          maxbits, n4);
  quantize_x<<<2048, 256, 0, stream>>>((const float4*)x, (const float4*)rcp,
                                       maxbits, (int*)xq, n4);

  dim3 grid(N_TOT / BN, M_TOT / BM);
  gemm_i8<<<grid, 512, 0, stream>>>(xq, wq8, maxbits, wscale, bias, out);
}

// Round 4
// 231.564 us; speedup vs baseline: 1.4837x; 1.0042x over previous
//
#include <hip/hip_runtime.h>
#include <stdint.h>

// Problem constants (B=4, S=2048 -> M = 8192 rows)
#define M_TOT 8192
#define N_TOT 4096
#define K_TOT 4096

typedef int v4i __attribute__((ext_vector_type(4)));

// GEMM tile config: 256x256 tile, BK=128 bytes of K, 8 waves (2M x 4N), 512 thr
#define BM 256
#define BN 256
#define BK 128
#define NT (K_TOT / BK)                    // 32 K-tiles
#define TILE_A_BYTES (BM * BK)             // 32 KB
#define TILE_B_BYTES (BN * BK)             // 32 KB
#define BUF_BYTES (TILE_A_BYTES + TILE_B_BYTES)  // 64 KB, x2 buffers = 128 KB LDS

// ---------------------------------------------------------------------------
// Kernel 0: rcp table  r[k] = 1/smooth[k]
// ---------------------------------------------------------------------------
__global__ void prep_rcp(const float* __restrict__ s, float* __restrict__ r) {
  int i = blockIdx.x * blockDim.x + threadIdx.x;
  if (i < K_TOT) r[i] = 1.0f / s[i];
}

// ---------------------------------------------------------------------------
// Kernel 1: pack weight int32 -> int8 (harness passes integer inputs as int32)
// ---------------------------------------------------------------------------
__global__ void pack_w(const int4* __restrict__ w32, int* __restrict__ w8, int n4) {
  int stride = gridDim.x * blockDim.x;
  for (int i = blockIdx.x * blockDim.x + threadIdx.x; i < n4; i += stride) {
    int4 v = w32[i];
    w8[i] = (v.x & 0xff) | ((v.y & 0xff) << 8) | ((v.z & 0xff) << 16) | (v.w << 24);
  }
}

// ---------------------------------------------------------------------------
// Kernel 2: global max(|x * rcp_s|) -> ws[0] as uint bits; 1 atomic per block
// ---------------------------------------------------------------------------
__global__ void reduce_maxabs(const float4* __restrict__ x,
                              const float4* __restrict__ rcp4,
                              unsigned int* __restrict__ maxbits, int n4) {
  float m = 0.0f;
  int stride = gridDim.x * blockDim.x;
  for (int i = blockIdx.x * blockDim.x + threadIdx.x; i < n4; i += stride) {
    float4 v = x[i];
    float4 r = rcp4[i & (K_TOT / 4 - 1)];
    m = fmaxf(m, fabsf(v.x * r.x));
    m = fmaxf(m, fabsf(v.y * r.y));
    m = fmaxf(m, fabsf(v.z * r.z));
    m = fmaxf(m, fabsf(v.w * r.w));
  }
#pragma unroll
  for (int off = 32; off; off >>= 1) m = fmaxf(m, __shfl_xor(m, off));
  __shared__ float sm[4];
  if ((threadIdx.x & 63) == 0) sm[threadIdx.x >> 6] = m;
  __syncthreads();
  if (threadIdx.x == 0) {
    float mm = fmaxf(fmaxf(sm[0], sm[1]), fmaxf(sm[2], sm[3]));
    atomicMax(maxbits, __float_as_uint(mm));
  }
}

// ---------------------------------------------------------------------------
// Kernel 3: quantize x -> int8 packed; q = clip(rint(x * rcp_s * inv_d))
// ---------------------------------------------------------------------------
__global__ void quantize_x(const float4* __restrict__ x,
                           const float4* __restrict__ rcp4,
                           const unsigned int* __restrict__ maxbits,
                           int* __restrict__ xq, int n4) {
  const float d = __uint_as_float(*maxbits) / 127.0f + 1e-5f;
  const float inv = 1.0f / d;
  int stride = gridDim.x * blockDim.x;
  for (int i = blockIdx.x * blockDim.x + threadIdx.x; i < n4; i += stride) {
    float4 v = x[i];
    float4 r = rcp4[i & (K_TOT / 4 - 1)];
    int q0 = (int)fminf(fmaxf(rintf(v.x * r.x * inv), -128.0f), 127.0f);
    int q1 = (int)fminf(fmaxf(rintf(v.y * r.y * inv), -128.0f), 127.0f);
    int q2 = (int)fminf(fmaxf(rintf(v.z * r.z * inv), -128.0f), 127.0f);
    int q3 = (int)fminf(fmaxf(rintf(v.w * r.w * inv), -128.0f), 127.0f);
    xq[i] = (q0 & 0xff) | ((q1 & 0xff) << 8) | ((q2 & 0xff) << 16) | (q3 << 24);
  }
}

// ---------------------------------------------------------------------------
// Kernel 4: int8 GEMM, 256x256 tile, BK=128, counted-vmcnt double buffer,
//           interleaved MFMA clusters (c1-c3 overlap in-flight ds_reads).
//
// Race-freedom argument (per K-tile iteration t, reading buf[t&1]):
//   1. 24 ds_read_b128 issued; clusters 1-3 (48 MFMA) run on partial sets
//      under compiler-counted lgkmcnt — register-only, no LDS hazard.
//   2. lgkmcnt(0) -> s_barrier  => every wave's reads of buf COMPLETED.
//   3. issue 8 global_load_lds for tile t+2 into buf (safe: reads done).
//   4. cluster 4 (16 MFMA).
//   5. s_waitcnt vmcnt(8): outstanding <= 16 (t+1's 8 + t+2's 8); drains the
//      OLDEST 8 = tile t+1's loads -> t+1 fully in LDS.
//   6. s_barrier => ALL waves' t+1 loads landed; next iter reads buf[(t+1)&1].
// vmcnt never drains to 0 in the loop (T4); loads span two barriers.
//
// LDS swizzle (T2): physical col = logical col ^ ((row&7)<<4), applied on the
// pre-swizzled GLOBAL source (global_load_lds writes linearly) and on ds_read.
// Measured R3: SQ_LDS_BANK_CONFLICT == 0.
// ---------------------------------------------------------------------------
__global__ __launch_bounds__(512, 2) void gemm_i8(
    const int8_t* __restrict__ Aq,   // [M][K]
    const int8_t* __restrict__ Wt,   // [N][K]
    const unsigned int* __restrict__ maxbits,
    const float* __restrict__ wscale,  // [N]
    const float* __restrict__ bias,    // [N]
    float* __restrict__ out) {         // [M][N]
  __shared__ int8_t lds[2 * BUF_BYTES];

  const int tid = threadIdx.x;
  const int lane = tid & 63;
  const int wid = tid >> 6;      // 0..7
  const int l16 = lane & 15;
  const int lhi = lane >> 4;     // 0..3

  // T1: XCD-aware block swizzle. 512 blocks, 512 % 8 == 0 -> simple bijective.
  // XCD r gets 64 consecutive tile ids = 4 contiguous M-panels (4 MB A = L2).
  const int flat = blockIdx.y * gridDim.x + blockIdx.x;
  const int swz = (flat & 7) * 64 + (flat >> 3);
  const int m0 = (swz / (N_TOT / BN)) * BM;
  const int n0 = (swz % (N_TOT / BN)) * BN;

  const int wave_m = wid >> 2;   // 0..1  -> 128 rows
  const int wave_n = wid & 3;    // 0..3  -> 64 cols

  // ---- staging: per wave 4 A-chunks + 4 B-chunks, 1 KB each (8 rows x 128B)
  const int roff = lane >> 3;                    // row within chunk 0..7
  const int csel = ((lane & 7) ^ roff) << 4;     // pre-swizzled 16B col block
  const int8_t* Abase = Aq + (size_t)m0 * K_TOT; // uniform
  const int8_t* Bbase = Wt + (size_t)n0 * K_TOT; // uniform
  int goff[4];
#pragma unroll
  for (int c = 0; c < 4; ++c) {
    int grow = (wid * 4 + c) * 8 + roff;         // 0..255
    goff[c] = grow * K_TOT + csel;
  }

  auto stage = [&](int dstbuf, int koff) {
#pragma unroll
    for (int c = 0; c < 4; ++c) {
      __builtin_amdgcn_global_load_lds(
          (const __attribute__((address_space(1))) void*)(Abase + goff[c] + koff),
          (__attribute__((address_space(3))) void*)(lds + dstbuf * BUF_BYTES + (wid * 4 + c) * 1024),
          16, 0, 0);
      __builtin_amdgcn_global_load_lds(
          (const __attribute__((address_space(1))) void*)(Bbase + goff[c] + koff),
          (__attribute__((address_space(3))) void*)(lds + dstbuf * BUF_BYTES + TILE_A_BYTES + (wid * 4 + c) * 1024),
          16, 0, 0);
    }
  };

  // ---- ds_read fragment addressing (swizzled) ----
  const int sw = (l16 & 7) << 4;
  const int colA0 = (0 * 64 + lhi * 16) ^ sw;   // kstep 0
  const int colA1 = (1 * 64 + lhi * 16) ^ sw;   // kstep 1
  const int aRow = (wave_m * 128 + l16) * BK;
  const int bRow = (wave_n * 64 + l16) * BK;

  // ---- prologue: stage tiles 0,1; wait tile 0 landed ----
  stage(0, 0);
  stage(1, BK);
  asm volatile("s_waitcnt vmcnt(8)" ::: "memory");
  __builtin_amdgcn_s_barrier();
  __builtin_amdgcn_sched_barrier(0);

  v4i acc[8][4] = {};

#pragma unroll 2
  for (int t = 0; t < NT; ++t) {
    const int buf = t & 1;
    const int8_t* Ab = lds + buf * BUF_BYTES;
    const int8_t* Bb = lds + buf * BUF_BYTES + TILE_A_BYTES;

    // reads in cluster-use order: (8) a0[0-3]+b0, (4) a0[4-7],
    //                             (8) a1[0-3]+b1, (4) a1[4-7]
    v4i a0[8], a1[8], b0[4], b1[4];
#pragma unroll
    for (int i = 0; i < 4; ++i) a0[i] = *(const v4i*)(Ab + aRow + i * 2048 + colA0);
#pragma unroll
    for (int j = 0; j < 4; ++j) b0[j] = *(const v4i*)(Bb + bRow + j * 2048 + colA0);
#pragma unroll
    for (int i = 4; i < 8; ++i) a0[i] = *(const v4i*)(Ab + aRow + i * 2048 + colA0);
#pragma unroll
    for (int i = 0; i < 4; ++i) a1[i] = *(const v4i*)(Ab + aRow + i * 2048 + colA1);
#pragma unroll
    for (int j = 0; j < 4; ++j) b1[j] = *(const v4i*)(Bb + bRow + j * 2048 + colA1);
#pragma unroll
    for (int i = 4; i < 8; ++i) a1[i] = *(const v4i*)(Ab + aRow + i * 2048 + colA1);

    // clusters 1-3: no sched pins -> compiler emits counted lgkmcnt,
    // MFMA overlaps the remaining in-flight ds_reads.
    __builtin_amdgcn_s_setprio(1);
#pragma unroll
    for (int i = 0; i < 4; ++i)
#pragma unroll
      for (int j = 0; j < 4; ++j)
        acc[i][j] = __builtin_amdgcn_mfma_i32_16x16x64_i8(a0[i], b0[j], acc[i][j], 0, 0, 0);
#pragma unroll
    for (int i = 4; i < 8; ++i)
#pragma unroll
      for (int j = 0; j < 4; ++j)
        acc[i][j] = __builtin_amdgcn_mfma_i32_16x16x64_i8(a0[i], b0[j], acc[i][j], 0, 0, 0);
#pragma unroll
    for (int i = 0; i < 4; ++i)
#pragma unroll
      for (int j = 0; j < 4; ++j)
        acc[i][j] = __builtin_amdgcn_mfma_i32_16x16x64_i8(a1[i], b1[j], acc[i][j], 0, 0, 0);
    __builtin_amdgcn_s_setprio(0);

    // all-waves read-drain, then reuse buf for tile t+2
    asm volatile("s_waitcnt lgkmcnt(0)" ::: "memory");
    __builtin_amdgcn_sched_barrier(0);
    __builtin_amdgcn_s_barrier();
    __builtin_amdgcn_sched_barrier(0);

    const int ts = (t + 2 < NT) ? (t + 2) : (NT - 1);
    stage(buf, ts * BK);
    __builtin_amdgcn_sched_barrier(0);

    // cluster 4 overlaps the staging loads
    __builtin_amdgcn_s_setprio(1);
#pragma unroll
    for (int i = 4; i < 8; ++i)
#pragma unroll
      for (int j = 0; j < 4; ++j)
        acc[i][j] = __builtin_amdgcn_mfma_i32_16x16x64_i8(a1[i], b1[j], acc[i][j], 0, 0, 0);
    __builtin_amdgcn_s_setprio(0);
    __builtin_amdgcn_sched_barrier(0);

    asm volatile("s_waitcnt vmcnt(8)" ::: "memory");
    __builtin_amdgcn_sched_barrier(0);
    __builtin_amdgcn_s_barrier();
    __builtin_amdgcn_sched_barrier(0);
  }

  // ---- epilogue: dequant + bias, C/D layout col=l16, row=lhi*4+reg ----
  const float ascale = __uint_as_float(*maxbits) / 127.0f;
#pragma unroll
  for (int i = 0; i < 8; ++i) {
    const int orow = m0 + wave_m * 128 + i * 16 + lhi * 4;
#pragma unroll
    for (int j = 0; j < 4; ++j) {
      const int ocol = n0 + wave_n * 64 + j * 16 + l16;
      const float wsc = wscale[ocol] * ascale;
      const float bb = bias[ocol];
#pragma unroll
      for (int r = 0; r < 4; ++r) {
        out[(size_t)(orow + r) * N_TOT + ocol] = (float)acc[i][j][r] * wsc + bb;
      }
    }
  }
}

// ---------------------------------------------------------------------------
extern "C" void kernel_launch(void* const* d_in, const int* in_sizes, int n_in,
                              void* d_out, int out_size, void* d_ws, size_t ws_size,
                              hipStream_t stream) {
  const float* x = (const float*)d_in[0];
  const int* w32 = (const int*)d_in[1];        // int8 in reference, int32 on device
  const float* wscale = (const float*)d_in[2];
  const float* smooth = (const float*)d_in[3];
  const float* bias = (const float*)d_in[4];
  float* out = (float*)d_out;

  unsigned int* maxbits = (unsigned int*)d_ws;
  float* rcp = (float*)((char*)d_ws + 1024);                 // 16 KB
  int8_t* xq = (int8_t*)d_ws + (1 << 20);                    // 32 MB
  int8_t* wq8 = xq + (size_t)M_TOT * K_TOT;                  // 16 MB

  hipMemsetAsync(d_ws, 0, 4, stream);  // zero the max accumulator each call

  prep_rcp<<<K_TOT / 256, 256, 0, stream>>>(smooth, rcp);

  const int nw4 = N_TOT * K_TOT / 4;
  pack_w<<<2048, 256, 0, stream>>>((const int4*)w32, (int*)wq8, nw4);

  const int n4 = M_TOT * K_TOT / 4;
  reduce_maxabs<<<2048, 256, 0, stream>>>((const float4*)x, (const float4*)rcp,
                                          maxbits, n4);
  quantize_x<<<2048, 256, 0, stream>>>((const float4*)x, (const float4*)rcp,
                                       maxbits, (int*)xq, n4);

  dim3 grid(N_TOT / BN, M_TOT / BM);
  gemm_i8<<<grid, 512, 0, stream>>>(xq, wq8, maxbits, wscale, bias, out);
}